// Round 1
// baseline (88.069 us; speedup 1.0000x reference)
//
#include <hip/hip_runtime.h>
#include <math.h>

#define N_GENES 20000
#define UNITS   10000
#define DEG     32
#define BATCH   128

// Kernel 1: featT[g][b] = |feature[b][g]|  -- 32x32 LDS tile transpose, fused abs.
// N_GENES = 625*32, BATCH = 4*32, so no bounds checks needed.
__global__ __launch_bounds__(256) void transpose_abs_kernel(
    const float* __restrict__ in, float* __restrict__ out)
{
    __shared__ float tile[32][33];                 // +1 pad: conflict-free both phases
    const int g0 = blockIdx.x * 32;
    const int b0 = blockIdx.y * 32;
    const int tx = threadIdx.x;                    // 0..31
    const int ty = threadIdx.y;                    // 0..7
#pragma unroll
    for (int i = 0; i < 32; i += 8) {
        tile[ty + i][tx] = fabsf(in[(size_t)(b0 + ty + i) * N_GENES + (g0 + tx)]);
    }
    __syncthreads();
#pragma unroll
    for (int i = 0; i < 32; i += 8) {
        out[(size_t)(g0 + ty + i) * BATCH + (b0 + tx)] = tile[tx][ty + i];
    }
}

// Kernel 2: block handles 16 units x all 128 batches.
// thread: b = tid&127 (batch lane), half = tid>>7 selects units [0..7] or [8..15].
// Gather loads are contiguous across batch lanes (256 B per wave-load).
__global__ __launch_bounds__(256) void gather_unit_kernel(
    const float* __restrict__ featT,
    const int*   __restrict__ ppi,
    const float* __restrict__ kernelw,
    const float* __restrict__ bias,
    float*       __restrict__ out)
{
    __shared__ int idx[16 * DEG];                  // 512 indices for this unit tile
    const int tid = threadIdx.x;
    const int u0  = blockIdx.x * 16;

    {
        const int* src = ppi + (size_t)u0 * DEG;
        idx[tid]       = src[tid];
        idx[tid + 256] = src[tid + 256];
    }
    __syncthreads();

    const int b     = tid & 127;
    const int ubase = (tid >> 7) * 8;              // 0 or 8

    float acc[8] = {0.f, 0.f, 0.f, 0.f, 0.f, 0.f, 0.f, 0.f};

#pragma unroll 4
    for (int d = 0; d < DEG; ++d) {
#pragma unroll
        for (int j = 0; j < 8; ++j) {
            const int g = idx[(ubase + j) * DEG + d];   // LDS broadcast (free)
            acc[j] += featT[(size_t)g * BATCH + b];     // coalesced across lanes
        }
    }

    float res[8];
#pragma unroll
    for (int j = 0; j < 8; ++j) {
        const int u = u0 + ubase + j;
        const float h = acc[j] * kernelw[u] + bias[u];
        // tanh(h) = 1 - 2/(exp(2h)+1); saturates correctly for |h| large
        const float e = __expf(2.f * h);
        res[j] = 1.f - 2.f / (e + 1.f);
    }

    // out[b][u0+ubase .. +7]: 32 contiguous bytes per thread, 16B-aligned
    float4* o = (float4*)(out + (size_t)b * UNITS + u0 + ubase);
    o[0] = make_float4(res[0], res[1], res[2], res[3]);
    o[1] = make_float4(res[4], res[5], res[6], res[7]);
}

extern "C" void kernel_launch(void* const* d_in, const int* in_sizes, int n_in,
                              void* d_out, int out_size, void* d_ws, size_t ws_size,
                              hipStream_t stream) {
    const float* feature = (const float*)d_in[0];
    const int*   ppi     = (const int*)d_in[1];
    const float* kernelw = (const float*)d_in[2];
    const float* bias    = (const float*)d_in[3];
    float* out   = (float*)d_out;
    float* featT = (float*)d_ws;                   // 20000*128*4 = 10.24 MB

    dim3 g1(N_GENES / 32, BATCH / 32);
    dim3 b1(32, 8);
    transpose_abs_kernel<<<g1, b1, 0, stream>>>(feature, featT);

    gather_unit_kernel<<<UNITS / 16, 256, 0, stream>>>(featT, ppi, kernelw, bias, out);
}

// Round 2
// 79.959 us; speedup vs baseline: 1.1014x; 1.1014x over previous
//
#include <hip/hip_runtime.h>
#include <hip/hip_fp16.h>
#include <math.h>

#define N_GENES 20000
#define UNITS   10000
#define DEG     32
#define BATCH   128

// Kernel 1: featT[g][b] = (half)|feature[b][g]| -- 32x32 LDS tile, fused abs+cvt.
__global__ __launch_bounds__(256) void transpose_abs_f16_kernel(
    const float* __restrict__ in, __half* __restrict__ out)
{
    __shared__ float tile[32][33];
    const int g0 = blockIdx.x * 32;
    const int b0 = blockIdx.y * 32;
    const int tx = threadIdx.x;   // 0..31
    const int ty = threadIdx.y;   // 0..7
#pragma unroll
    for (int i = 0; i < 32; i += 8)
        tile[ty + i][tx] = fabsf(in[(size_t)(b0 + ty + i) * N_GENES + (g0 + tx)]);
    __syncthreads();
#pragma unroll
    for (int i = 0; i < 32; i += 8)
        out[(size_t)(g0 + ty + i) * BATCH + (b0 + tx)] = __float2half(tile[tx][ty + i]);
}

// Kernel 2: block = 4 waves, 8 units/block (1250 blocks, exact).
// Wave w handles units u0+2w, u0+2w+1; lane covers batches 2*lane, 2*lane+1.
// One __half2 load per (unit,d) = 64 lanes x 4 B = full 256 B gene row.
__global__ __launch_bounds__(256) void gather_unit_kernel(
    const __half2* __restrict__ featT,   // [N_GENES][64] half2 rows
    const int*   __restrict__ ppi,
    const float* __restrict__ kernelw,
    const float* __restrict__ bias,
    float*       __restrict__ out)
{
    __shared__ int idx[8 * DEG];         // 256 indices = block size
    const int tid = threadIdx.x;
    const int u0  = blockIdx.x * 8;

    idx[tid] = ppi[(size_t)u0 * DEG + tid];
    __syncthreads();

    const int lane = tid & 63;
    const int w    = tid >> 6;           // 0..3
    const int ub   = w * 2;              // local unit base

    float2 acc0 = {0.f, 0.f}, acc1 = {0.f, 0.f};

#pragma unroll 8
    for (int d = 0; d < DEG; ++d) {
        const int g0 = idx[ub * DEG + d];        // LDS broadcast
        const int g1 = idx[(ub + 1) * DEG + d];
        const float2 f0 = __half22float2(featT[(size_t)g0 * 64 + lane]);
        const float2 f1 = __half22float2(featT[(size_t)g1 * 64 + lane]);
        acc0.x += f0.x; acc0.y += f0.y;
        acc1.x += f1.x; acc1.y += f1.y;
    }

    const int u  = u0 + ub;
    const float k0 = kernelw[u],     k1 = kernelw[u + 1];
    const float c0 = bias[u],        c1 = bias[u + 1];

    // tanh(h) = 1 - 2/(exp(2h)+1)
    const float h00 = acc0.x * k0 + c0;
    const float h01 = acc1.x * k1 + c1;
    const float h10 = acc0.y * k0 + c0;
    const float h11 = acc1.y * k1 + c1;
    const float r00 = 1.f - 2.f / (__expf(2.f * h00) + 1.f);
    const float r01 = 1.f - 2.f / (__expf(2.f * h01) + 1.f);
    const float r10 = 1.f - 2.f / (__expf(2.f * h10) + 1.f);
    const float r11 = 1.f - 2.f / (__expf(2.f * h11) + 1.f);

    const int b = lane * 2;
    *(float2*)(out + (size_t)b       * UNITS + u) = make_float2(r00, r01);
    *(float2*)(out + (size_t)(b + 1) * UNITS + u) = make_float2(r10, r11);
}

extern "C" void kernel_launch(void* const* d_in, const int* in_sizes, int n_in,
                              void* d_out, int out_size, void* d_ws, size_t ws_size,
                              hipStream_t stream) {
    const float* feature = (const float*)d_in[0];
    const int*   ppi     = (const int*)d_in[1];
    const float* kernelw = (const float*)d_in[2];
    const float* bias    = (const float*)d_in[3];
    float* out   = (float*)d_out;
    __half* featT = (__half*)d_ws;                 // 20000*128*2 = 5.12 MB

    dim3 g1(N_GENES / 32, BATCH / 32);
    dim3 b1(32, 8);
    transpose_abs_f16_kernel<<<g1, b1, 0, stream>>>(feature, featT);

    gather_unit_kernel<<<UNITS / 8, 256, 0, stream>>>(
        (const __half2*)featT, ppi, kernelw, bias, out);
}